// Round 2
// baseline (297.198 us; speedup 1.0000x reference)
//
#include <hip/hip_runtime.h>

// EIT3Attention: B=4, Sq=Sk=2048, d_model=2048, H=16, Dh=128, fp32 I/O.
// R2: prepass dequants K/V -> bf16 into d_ws (K row-major XOR-swizzled,
// V transposed [d][k] XOR-swizzled), main kernel = 8-wave flash attention,
// QROWS=64/wave (2x fragment reuse), KVB=32, global_load_lds staging,
// 2-phase double buffer, defer-max online softmax.

typedef __attribute__((ext_vector_type(8))) short short8;
typedef __attribute__((ext_vector_type(16))) float f32x16;

#define DEVI __device__ __forceinline__

namespace {

constexpr int DM = 2048;   // d_model
constexpr int SQ = 2048;
constexpr int SK = 2048;
constexpr int DH = 128;
constexpr int KVB = 32;            // kv rows per tile
constexpr int NT = SK / KVB;       // 64 tiles
// (1/sqrt(128)) * log2(e)
constexpr float CEXP = 0.12752051393f;
constexpr float DEFER = 62.0f;     // raw-score defer-max threshold (~e^8)

union US8 { unsigned short u[8]; short8 v; };
union UV2 { unsigned long long q[2]; short8 v; };
union UP4 { unsigned int u[4]; short8 v; };

DEVI unsigned short f2bf(float f) {            // fp32 -> bf16 RNE
  unsigned int u = __float_as_uint(f);
  return (unsigned short)((u + 0x7fffu + ((u >> 16) & 1u)) >> 16);
}

DEVI float dq(float x) {                       // int4 quant-dequant, matches ref
  float t = __builtin_rintf(__builtin_fmaf(x, 20.0f, 8.0f));  // round half-even
  t = __builtin_fmaxf(t, 0.0f);
  t = __builtin_fminf(t, 15.0f);
  return (t - 8.0f) * 0.05f;
}

DEVI unsigned short dqb(float x) { return f2bf(dq(x)); }

} // namespace

// ---------------------------------------------------------------------------
// Prepass: dequant K/V to bf16 in ws.
// K ws layout: per (b,h,tile t of 32 rows): elem u = (n*128 + d) ^ ((n&7)<<3)
// V ws layout: transposed: elem u = d*32 + (k ^ (((d>>1)&3)<<3))
// Both layouts are exactly the (linear-copy) LDS image the main kernel reads.
// ---------------------------------------------------------------------------
__global__ __launch_bounds__(512)
void eit3_pre(const float* __restrict__ kg, const float* __restrict__ vg,
              unsigned short* __restrict__ kws, unsigned short* __restrict__ vws)
{
  const int tid = threadIdx.x;
  const int t = blockIdx.x, h = blockIdx.y, b = blockIdx.z;
  const size_t tb = (((size_t)(b * 16 + h)) * NT + t) * 4096;
  __shared__ __align__(16) unsigned short VL[32 * 136];   // padded stride 136

  // ---- K: dest-driven (swizzle is self-inverse on the d field) ----
  {
    const int g = tid;                      // 512 groups of 8 elems
    const int n = g >> 4;
    const int dsw = ((g & 15) * 8) ^ ((n & 7) << 3);
    const float* src = kg + ((size_t)b * SK + (size_t)t * KVB + n) * DM + h * DH + dsw;
    float4 fa = *(const float4*)src;
    float4 fb = *(const float4*)(src + 4);
    US8 o;
    o.u[0] = dqb(fa.x); o.u[1] = dqb(fa.y); o.u[2] = dqb(fa.z); o.u[3] = dqb(fa.w);
    o.u[4] = dqb(fb.x); o.u[5] = dqb(fb.y); o.u[6] = dqb(fb.z); o.u[7] = dqb(fb.w);
    *(short8*)(kws + tb + (size_t)g * 8) = o.v;
  }
  // ---- V rows -> LDS (dequant, coalesced read) ----
  {
    const int r = tid >> 4, d0 = (tid & 15) * 8;
    const float* src = vg + ((size_t)b * SK + (size_t)t * KVB + r) * DM + h * DH + d0;
    float4 fa = *(const float4*)src;
    float4 fb = *(const float4*)(src + 4);
    US8 o;
    o.u[0] = dqb(fa.x); o.u[1] = dqb(fa.y); o.u[2] = dqb(fa.z); o.u[3] = dqb(fa.w);
    o.u[4] = dqb(fb.x); o.u[5] = dqb(fb.y); o.u[6] = dqb(fb.z); o.u[7] = dqb(fb.w);
    *(short8*)(VL + r * 136 + d0) = o.v;
  }
  __syncthreads();
  // ---- Vt: dest-driven transpose out of LDS, coalesced 16B writes ----
  {
    const int g = tid;
    const int d = g >> 2;
    const int kb = ((g & 3) * 8) ^ (((d >> 1) & 3) << 3);
    US8 o;
#pragma unroll
    for (int i = 0; i < 8; ++i) o.u[i] = VL[(kb + i) * 136 + d];
    *(short8*)(vws + tb + (size_t)g * 8) = o.v;
  }
}

// ---------------------------------------------------------------------------
// Main attention kernel (fast path: bf16 K/V from ws).
// ---------------------------------------------------------------------------

DEVI void proc_sub(f32x16& st, float& M, float& L, f32x16 acc[4], short8 pa[2],
                   int hi, bool fast, const unsigned char* msk, int kv0,
                   long long qlim)
{
  if (!fast) {
#pragma unroll
    for (int r = 0; r < 16; ++r) {
      int nl = (r & 3) + 8 * (r >> 2) + 4 * hi;
      bool ok = (msk[nl] != 0) && ((long long)(kv0 + nl) <= qlim);
      if (!ok) st[r] = -3.0e38f;
    }
  }
  // max reduce (16 in-lane + pair lane^32)
  float t8[8];
#pragma unroll
  for (int i = 0; i < 8; ++i) t8[i] = __builtin_fmaxf(st[i], st[i + 8]);
#pragma unroll
  for (int i = 0; i < 4; ++i) t8[i] = __builtin_fmaxf(t8[i], t8[i + 4]);
  float pmax = __builtin_fmaxf(__builtin_fmaxf(t8[0], t8[1]),
                               __builtin_fmaxf(t8[2], t8[3]));
  pmax = __builtin_fmaxf(pmax, __shfl_xor(pmax, 32));
  // defer-max (T13): only rescale when max grows by > DEFER
  if (!__all(pmax <= M + DEFER)) {
    float Mn = __builtin_fmaxf(M, pmax);
    float sc = __builtin_amdgcn_exp2f((M - Mn) * CEXP);
    L *= sc;
#pragma unroll
    for (int r = 0; r < 16; ++r) {
      float s2 = __shfl(sc, (r & 3) + 8 * (r >> 2) + 4 * hi);
      acc[0][r] *= s2; acc[1][r] *= s2; acc[2][r] *= s2; acc[3][r] *= s2;
    }
    M = Mn;
  }
#pragma unroll
  for (int r = 0; r < 16; ++r)
    st[r] = __builtin_amdgcn_exp2f((st[r] - M) * CEXP);
  if (!fast) {
#pragma unroll
    for (int r = 0; r < 16; ++r) {
      int nl = (r & 3) + 8 * (r >> 2) + 4 * hi;
      bool ok = (msk[nl] != 0) && ((long long)(kv0 + nl) <= qlim);
      if (!ok) st[r] = 0.0f;
    }
  }
  // sum
  float s8[8];
#pragma unroll
  for (int i = 0; i < 8; ++i) s8[i] = st[i] + st[i + 8];
#pragma unroll
  for (int i = 0; i < 4; ++i) s8[i] = s8[i] + s8[i + 4];
  float ps = (s8[0] + s8[1]) + (s8[2] + s8[3]);
  ps += __shfl_xor(ps, 32);
  L += ps;
  // P -> bf16 A-frags (cvt_pk + permlane32_swap, validated R1 pattern)
#pragma unroll
  for (int ks = 0; ks < 2; ++ks) {
    const int m8 = ks * 8;
    unsigned int X0, X1, Y0, Y1;
    asm("v_cvt_pk_bf16_f32 %0, %1, %2" : "=v"(X0) : "v"(st[m8 + 0]), "v"(st[m8 + 1]));
    asm("v_cvt_pk_bf16_f32 %0, %1, %2" : "=v"(X1) : "v"(st[m8 + 2]), "v"(st[m8 + 3]));
    asm("v_cvt_pk_bf16_f32 %0, %1, %2" : "=v"(Y0) : "v"(st[m8 + 4]), "v"(st[m8 + 5]));
    asm("v_cvt_pk_bf16_f32 %0, %1, %2" : "=v"(Y1) : "v"(st[m8 + 6]), "v"(st[m8 + 7]));
    asm("v_permlane32_swap_b32 %0, %1" : "+v"(X0), "+v"(Y0));
    asm("v_permlane32_swap_b32 %0, %1" : "+v"(X1), "+v"(Y1));
    UP4 P;
    P.u[0] = X0; P.u[1] = X1; P.u[2] = Y0; P.u[3] = Y1;
    pa[ks] = P.v;
  }
}

__global__ __launch_bounds__(512)
void eit3_attn(const unsigned short* __restrict__ kws,
               const unsigned short* __restrict__ vws,
               const float* __restrict__ qg,
               const unsigned char* __restrict__ maskg,
               const int* __restrict__ qsg, float* __restrict__ outg)
{
  const int tid  = threadIdx.x;
  const int lane = tid & 63;
  const int w    = tid >> 6;
  const int hi   = lane >> 5;
  const int ql   = lane & 31;
  const int hi8  = hi * 8;
  // XCD-grouped decode: 8 (b,h) pairs per XCD; 4 q-blocks of a pair co-located
  const int phys = blockIdx.x;              // 0..255
  const int xcd = phys & 7, slot = phys >> 3;
  const int bh = (slot >> 2) * 8 + xcd;
  const int qb = slot & 3;
  const int h = bh & 15, b = bh >> 4;
  const int q0 = qb * 512;
  const long long qstart = (long long)qsg[0];

  __shared__ __align__(16) unsigned short Ksh[2][4096];
  __shared__ __align__(16) unsigned short Vsh[2][4096];
  __shared__ unsigned char mskSh[2][32];

  // ---- robust all-true mask check (u8 or i32 bool layouts) ----
  const unsigned char* mrow = maskg + (size_t)b * SK;
  int ok_u8, ok_i32;
  {
    const unsigned char* p4 = mrow + tid * 4;
    unsigned char b0 = p4[0], b1 = p4[1], b2 = p4[2], b3 = p4[3];
    ok_u8  = (b0 && b1 && b2 && b3);
    ok_i32 = (b0 && !b1 && !b2 && !b3);
  }
  const int a_u8  = __syncthreads_and(ok_u8);
  const int a_i32 = __syncthreads_and(ok_i32);
  const bool mask_all = (a_u8 | a_i32) != 0;

  // ---- Q fragments for 2 q-subtiles (B-operand of swapped QK^T) ----
  short8 qf0[8], qf1[8];
  {
    const float* qp0 = qg + ((size_t)b * SQ + q0 + w * 64 + ql) * DM + h * DH + hi8;
#pragma unroll
    for (int s = 0; s < 8; ++s) {
      float4 a0 = *(const float4*)(qp0 + s * 16);
      float4 c0 = *(const float4*)(qp0 + s * 16 + 4);
      float4 a1 = *(const float4*)(qp0 + 32 * DM + s * 16);
      float4 c1 = *(const float4*)(qp0 + 32 * DM + s * 16 + 4);
      US8 t0, t1;
      t0.u[0] = f2bf(a0.x); t0.u[1] = f2bf(a0.y); t0.u[2] = f2bf(a0.z); t0.u[3] = f2bf(a0.w);
      t0.u[4] = f2bf(c0.x); t0.u[5] = f2bf(c0.y); t0.u[6] = f2bf(c0.z); t0.u[7] = f2bf(c0.w);
      t1.u[0] = f2bf(a1.x); t1.u[1] = f2bf(a1.y); t1.u[2] = f2bf(a1.z); t1.u[3] = f2bf(a1.w);
      t1.u[4] = f2bf(c1.x); t1.u[5] = f2bf(c1.y); t1.u[6] = f2bf(c1.z); t1.u[7] = f2bf(c1.w);
      qf0[s] = t0.v; qf1[s] = t1.v;
    }
  }

  f32x16 zv;
#pragma unroll
  for (int r = 0; r < 16; ++r) zv[r] = 0.0f;
  f32x16 acc0[4], acc1[4];
#pragma unroll
  for (int n = 0; n < 4; ++n) { acc0[n] = zv; acc1[n] = zv; }
  float M0 = -3.0e38f, L0 = 0.0f, M1 = -3.0e38f, L1 = 0.0f;

  const size_t tbase = (size_t)bh * NT * 4096;
  const unsigned short* Kf = &Ksh[0][0];
  const unsigned short* Vf = &Vsh[0][0];
  const int xr = (ql & 7) << 3;        // K-row swizzle (lane-const)
  const int xv = ((ql >> 1) & 3) << 3; // Vt-row swizzle (lane-const)

  // stage tile t into buffer buf via global_load_lds (1 KiB per wave per tensor)
  auto stage = [&](int buf, int t) {
    const unsigned short* kt = kws + tbase + (size_t)t * 4096 + w * 512 + lane * 8;
    const unsigned short* vt = vws + tbase + (size_t)t * 4096 + w * 512 + lane * 8;
    __builtin_amdgcn_global_load_lds(
        (const __attribute__((address_space(1))) void*)kt,
        (__attribute__((address_space(3))) void*)((char*)&Ksh[0][0] + buf * 8192 + w * 1024),
        16, 0, 0);
    __builtin_amdgcn_global_load_lds(
        (const __attribute__((address_space(1))) void*)vt,
        (__attribute__((address_space(3))) void*)((char*)&Vsh[0][0] + buf * 8192 + w * 1024),
        16, 0, 0);
  };

  // prologue
  stage(0, 0);
  {
    bool f0 = mask_all && (31LL <= qstart + (long long)q0);
    if (!f0 && w == 0 && lane < 32) mskSh[0][lane] = mrow[lane];
  }
  __syncthreads();

  int cur = 0;
  for (int ti = 0; ti < NT; ++ti) {
    const int kv0 = ti * KVB;
    const int nxt = cur ^ 1;
    if (ti + 1 < NT) {
      stage(nxt, ti + 1);
      bool fn = mask_all && ((long long)(kv0 + 2 * KVB - 1) <= qstart + (long long)q0);
      if (!fn && w == 0 && lane < 32) mskSh[nxt][lane] = mrow[kv0 + KVB + lane];
    }
    const bool fast = mask_all && ((long long)(kv0 + KVB - 1) <= qstart + (long long)q0);

    // ---- QK^T (swapped): each K-frag feeds both q-subtiles ----
    const unsigned short* Kc = Kf + cur * 4096;
    const unsigned short* Vc = Vf + cur * 4096;
    f32x16 st0 = zv, st1 = zv;
#pragma unroll
    for (int s = 0; s < 8; ++s) {
      short8 kf = *(const short8*)(Kc + ql * 128 + ((s * 16 + hi8) ^ xr));
      st0 = __builtin_amdgcn_mfma_f32_32x32x16_bf16(kf, qf0[s], st0, 0, 0, 0);
      st1 = __builtin_amdgcn_mfma_f32_32x32x16_bf16(kf, qf1[s], st1, 0, 0, 0);
    }

    // ---- online softmax per subtile ----
    short8 pa0[2], pa1[2];
    const long long qlim0 = qstart + (long long)(q0 + w * 64 + ql);
    proc_sub(st0, M0, L0, acc0, pa0, hi, fast, &mskSh[cur][0], kv0, qlim0);
    proc_sub(st1, M1, L1, acc1, pa1, hi, fast, &mskSh[cur][0], kv0, qlim0 + 32);

    // ---- PV: each Vt-frag feeds both q-subtiles ----
#pragma unroll
    for (int n = 0; n < 4; ++n) {
#pragma unroll
      for (int ks = 0; ks < 2; ++ks) {
        short8 vb = *(const short8*)(Vc + n * 1024 + ql * 32 + ((ks * 16 + hi8) ^ xv));
        acc0[n] = __builtin_amdgcn_mfma_f32_32x32x16_bf16(pa0[ks], vb, acc0[n], 0, 0, 0);
        acc1[n] = __builtin_amdgcn_mfma_f32_32x32x16_bf16(pa1[ks], vb, acc1[n], 0, 0, 0);
      }
    }

    __syncthreads();   // prefetch landed (compiler drains vmcnt) + reads done
    cur = nxt;
  }

  // ---- epilogue ----
  if (L0 == 0.0f) L0 = 1.0f;
  if (L1 == 0.0f) L1 = 1.0f;
  float ri0 = 1.0f / L0, ri1 = 1.0f / L1;
#pragma unroll
  for (int r = 0; r < 16; ++r) {
    int cr = (r & 3) + 8 * (r >> 2) + 4 * hi;
    float i0 = __shfl(ri0, cr), i1 = __shfl(ri1, cr);
    float* op0 = outg + ((size_t)b * SQ + q0 + w * 64 + cr) * DM + h * DH + ql;
    float* op1 = op0 + 32 * DM;
    op0[0]  = acc0[0][r] * i0;
    op0[32] = acc0[1][r] * i0;
    op0[64] = acc0[2][r] * i0;
    op0[96] = acc0[3][r] * i0;
    op1[0]  = acc1[0][r] * i1;
    op1[32] = acc1[1][r] * i1;
    op1[64] = acc1[2][r] * i1;
    op1[96] = acc1[3][r] * i1;
  }
}

// ---------------------------------------------------------------------------
// Fallback (R1 kernel, in-kernel dequant) — used only if ws is too small.
// ---------------------------------------------------------------------------
__global__ __launch_bounds__(512, 2)
void eit3_attn_fb(const float* __restrict__ qg, const float* __restrict__ kg,
                  const float* __restrict__ vg, const unsigned char* __restrict__ maskg,
                  const int* __restrict__ qsg, float* __restrict__ outg)
{
  const int tid  = threadIdx.x;
  const int lane = tid & 63;
  const int w    = tid >> 6;
  const int hi   = lane >> 5;
  const int ql   = lane & 31;
  const int qb = blockIdx.x;
  const int h  = blockIdx.y;
  const int b  = blockIdx.z;
  const int q0 = qb * 256;
  const long long qstart = (long long)qsg[0];

  __shared__ __align__(16) unsigned short Ksh[64 * 128];
  __shared__ __align__(16) unsigned short Vsh[64 * 128];
  __shared__ unsigned char mskSh[64];

  const unsigned int vbase = (unsigned int)(size_t)(void*)Vsh;

  const unsigned char* mrow = maskg + (size_t)b * SK;
  int ok_u8, ok_i32;
  {
    const unsigned char* p4 = mrow + tid * 4;
    unsigned char b0 = p4[0], b1 = p4[1], b2 = p4[2], b3 = p4[3];
    ok_u8  = (b0 && b1 && b2 && b3);
    ok_i32 = (b0 && !b1 && !b2 && !b3);
  }
  const int a_u8  = __syncthreads_and(ok_u8);
  const int a_i32 = __syncthreads_and(ok_i32);
  const bool mask_all = (a_u8 | a_i32) != 0;

  short8 qf[8];
  {
    const int qrow = q0 + w * 32 + ql;
    const float* qp = qg + ((size_t)b * SQ + qrow) * DM + h * DH + hi * 8;
#pragma unroll
    for (int s = 0; s < 8; ++s) {
      float4 fa = *(const float4*)(qp + s * 16);
      float4 fb = *(const float4*)(qp + s * 16 + 4);
      US8 t;
      t.u[0] = f2bf(fa.x); t.u[1] = f2bf(fa.y); t.u[2] = f2bf(fa.z); t.u[3] = f2bf(fa.w);
      t.u[4] = f2bf(fb.x); t.u[5] = f2bf(fb.y); t.u[6] = f2bf(fb.z); t.u[7] = f2bf(fb.w);
      qf[s] = t.v;
    }
  }

  f32x16 zv;
#pragma unroll
  for (int r = 0; r < 16; ++r) zv[r] = 0.0f;
  f32x16 acc[4];
  acc[0] = zv; acc[1] = zv; acc[2] = zv; acc[3] = zv;
  float M = -3.0e38f, L = 0.0f;

  const float* kptr = kg + ((size_t)b * SK) * DM + h * DH;
  const float* vptr = vg + ((size_t)b * SK) * DM + h * DH;

  for (int kv0 = 0; kv0 < SK; kv0 += 64) {
    __syncthreads();
#pragma unroll
    for (int j = 0; j < 2; ++j) {
      int idx = tid + 512 * j;
      int n = idx >> 4, d8 = idx & 15;
      const float* gp = kptr + (size_t)(kv0 + n) * DM + d8 * 8;
      float4 fa = *(const float4*)gp;
      float4 fb = *(const float4*)(gp + 4);
      US8 t;
      t.u[0] = dqb(fa.x); t.u[1] = dqb(fa.y); t.u[2] = dqb(fa.z); t.u[3] = dqb(fa.w);
      t.u[4] = dqb(fb.x); t.u[5] = dqb(fb.y); t.u[6] = dqb(fb.z); t.u[7] = dqb(fb.w);
      int ui = (n * 128 + d8 * 8) ^ ((n & 7) << 3);
      *(short8*)(Ksh + ui) = t.v;
    }
    {
      int kr = w * 8 + (lane & 7);
      int c3 = lane >> 3;
#pragma unroll
      for (int j = 0; j < 4; ++j) {
        int d4 = c3 + 8 * j;
        const float* gp = vptr + (size_t)(kv0 + kr) * DM + d4 * 4;
        float4 fa = *(const float4*)gp;
        ushort4 tv;
        tv.x = dqb(fa.x); tv.y = dqb(fa.y); tv.z = dqb(fa.z); tv.w = dqb(fa.w);
        int d = d4 * 4;
        int ui = ((kr >> 2) * 8 + (d >> 4)) * 64 + (kr & 3) * 16 + (d & 15);
        *(ushort4*)(Vsh + ui) = tv;
      }
    }
    const bool causal_ok = ((long long)kv0 + 63) <= (qstart + (long long)q0);
    const bool fast = mask_all && causal_ok;
    if (!fast && w == 0) mskSh[lane] = mrow[kv0 + lane];
    __syncthreads();

    f32x16 st[2];
#pragma unroll
    for (int t = 0; t < 2; ++t) {
      f32x16 sa = zv;
#pragma unroll
      for (int s = 0; s < 8; ++s) {
        int kr = t * 32 + ql;
        int ui = (kr * 128 + s * 16 + hi * 8) ^ ((kr & 7) << 3);
        short8 af = *(const short8*)(Ksh + ui);
        sa = __builtin_amdgcn_mfma_f32_32x32x16_bf16(af, qf[s], sa, 0, 0, 0);
      }
      st[t] = sa;
    }
    if (!fast) {
      const long long qlim = qstart + (long long)(q0 + w * 32 + ql);
#pragma unroll
      for (int t = 0; t < 2; ++t) {
#pragma unroll
        for (int r = 0; r < 16; ++r) {
          int nl = t * 32 + (r & 3) + 8 * (r >> 2) + 4 * hi;
          bool ok = (mskSh[nl] != 0) && ((long long)(kv0 + nl) <= qlim);
          if (!ok) st[t][r] = -3.0e38f;
        }
      }
    }
    f32x16 red;
#pragma unroll
    for (int r = 0; r < 16; ++r) red[r] = __builtin_fmaxf(st[0][r], st[1][r]);
#pragma unroll
    for (int r = 0; r < 8; ++r) red[r] = __builtin_fmaxf(red[r], red[r + 8]);
#pragma unroll
    for (int r = 0; r < 4; ++r) red[r] = __builtin_fmaxf(red[r], red[r + 4]);
    float pmax = __builtin_fmaxf(__builtin_fmaxf(red[0], red[1]),
                                 __builtin_fmaxf(red[2], red[3]));
    pmax = __builtin_fmaxf(pmax, __shfl_xor(pmax, 32));
    const float Mnew = __builtin_fmaxf(M, pmax);
    const float scale = __builtin_amdgcn_exp2f((M - Mnew) * CEXP);
#pragma unroll
    for (int t = 0; t < 2; ++t) {
#pragma unroll
      for (int r = 0; r < 16; ++r)
        st[t][r] = __builtin_amdgcn_exp2f((st[t][r] - Mnew) * CEXP);
    }
    if (!fast) {
      const long long qlim = qstart + (long long)(q0 + w * 32 + ql);
#pragma unroll
      for (int t = 0; t < 2; ++t) {
#pragma unroll
        for (int r = 0; r < 16; ++r) {
          int nl = t * 32 + (r & 3) + 8 * (r >> 2) + 4 * hi;
          bool ok = (mskSh[nl] != 0) && ((long long)(kv0 + nl) <= qlim);
          if (!ok) st[t][r] = 0.0f;
        }
      }
    }
    f32x16 sx;
#pragma unroll
    for (int r = 0; r < 16; ++r) sx[r] = st[0][r] + st[1][r];
#pragma unroll
    for (int r = 0; r < 8; ++r) sx[r] = sx[r] + sx[r + 8];
#pragma unroll
    for (int r = 0; r < 4; ++r) sx[r] = sx[r] + sx[r + 4];
    float ps = (sx[0] + sx[1]) + (sx[2] + sx[3]);
    ps += __shfl_xor(ps, 32);
    L = L * scale + ps;
    if (!__all(Mnew == M)) {
#pragma unroll
      for (int r = 0; r < 16; ++r) {
        float sc = __shfl(scale, (r & 3) + 8 * (r >> 2) + 4 * hi);
        acc[0][r] *= sc; acc[1][r] *= sc; acc[2][r] *= sc; acc[3][r] *= sc;
      }
    }
    M = Mnew;

    short8 pa[4];
#pragma unroll
    for (int ks = 0; ks < 4; ++ks) {
      const int t = ks >> 1;
      const int m8 = (ks & 1) * 8;
      unsigned int X0, X1, Y0, Y1;
      asm("v_cvt_pk_bf16_f32 %0, %1, %2" : "=v"(X0) : "v"(st[t][m8 + 0]), "v"(st[t][m8 + 1]));
      asm("v_cvt_pk_bf16_f32 %0, %1, %2" : "=v"(X1) : "v"(st[t][m8 + 2]), "v"(st[t][m8 + 3]));
      asm("v_cvt_pk_bf16_f32 %0, %1, %2" : "=v"(Y0) : "v"(st[t][m8 + 4]), "v"(st[t][m8 + 5]));
      asm("v_cvt_pk_bf16_f32 %0, %1, %2" : "=v"(Y1) : "v"(st[t][m8 + 6]), "v"(st[t][m8 + 7]));
      asm("v_permlane32_swap_b32 %0, %1" : "+v"(X0), "+v"(Y0));
      asm("v_permlane32_swap_b32 %0, %1" : "+v"(X1), "+v"(Y1));
      UP4 P;
      P.u[0] = X0; P.u[1] = X1; P.u[2] = Y0; P.u[3] = Y1;
      pa[ks] = P.v;
    }
#pragma unroll
    for (int n = 0; n < 4; ++n) {
      unsigned long long t0[4], t1[4];
#pragma unroll
      for (int ks = 0; ks < 4; ++ks) {
        unsigned int addr = vbase
          + (unsigned int)(((4 * ks + 2 * hi) * 8 + 2 * n + ((lane >> 4) & 1)) * 128)
          + (unsigned int)((lane & 15) * 8);
        asm volatile("ds_read_b64_tr_b16 %0, %1" : "=v"(t0[ks]) : "v"(addr));
        asm volatile("ds_read_b64_tr_b16 %0, %1 offset:1024" : "=v"(t1[ks]) : "v"(addr));
      }
      asm volatile("s_waitcnt lgkmcnt(0)" ::: "memory");
      __builtin_amdgcn_sched_barrier(0);
#pragma unroll
      for (int ks = 0; ks < 4; ++ks) {
        UV2 vb;
        vb.q[0] = t0[ks]; vb.q[1] = t1[ks];
        acc[n] = __builtin_amdgcn_mfma_f32_32x32x16_bf16(pa[ks], vb.v, acc[n], 0, 0, 0);
      }
    }
  }

  if (L == 0.0f) L = 1.0f;
  float rinv = 1.0f / L;
#pragma unroll
  for (int r = 0; r < 16; ++r) {
    int cr = (r & 3) + 8 * (r >> 2) + 4 * hi;
    float inv = __shfl(rinv, cr);
    float* op = outg + ((size_t)b * SQ + (q0 + w * 32 + cr)) * DM + h * DH + ql;
    op[0]  = acc[0][r] * inv;
    op[32] = acc[1][r] * inv;
    op[64] = acc[2][r] * inv;
    op[96] = acc[3][r] * inv;
  }
}

extern "C" void kernel_launch(void* const* d_in, const int* in_sizes, int n_in,
                              void* d_out, int out_size, void* d_ws, size_t ws_size,
                              hipStream_t stream) {
  (void)in_sizes; (void)n_in; (void)out_size;
  const float* q = (const float*)d_in[0];
  const float* k = (const float*)d_in[1];
  const float* v = (const float*)d_in[2];
  const unsigned char* mask = (const unsigned char*)d_in[3];
  const int* qs = (const int*)d_in[4];

  const size_t need = (size_t)2 * 16777216 * 2;   // K + V bf16 = 64 MiB
  if (ws_size >= need) {
    unsigned short* kws = (unsigned short*)d_ws;
    unsigned short* vws = kws + 16777216;
    dim3 pgrid(NT, 16, 4);
    eit3_pre<<<pgrid, dim3(512), 0, stream>>>(k, v, kws, vws);
    eit3_attn<<<dim3(256), dim3(512), 0, stream>>>(kws, vws, q, mask, qs, (float*)d_out);
  } else {
    dim3 grid(SQ / 256, 16, 4);
    eit3_attn_fb<<<grid, dim3(512), 0, stream>>>(q, k, v, mask, qs, (float*)d_out);
  }
}

// Round 3
// 296.074 us; speedup vs baseline: 1.0038x; 1.0038x over previous
//
#include <hip/hip_runtime.h>

// EIT3Attention: B=4, Sq=Sk=2048, d_model=2048, H=16, Dh=128, fp32 I/O.
// R3: prepass dequants K/V -> bf16 ws (K row-major XOR-swizzled, V^T
// XOR-swizzled). Main: 4-wave/256-thr blocks, QROWS=64/wave (2x reuse),
// KVB=32, grid 512 (2 blocks/CU), global_load_lds staging, double buffer.
// R2 lesson: __launch_bounds__ must grant the ~240 VGPRs (R2 spilled ~120).

typedef __attribute__((ext_vector_type(8))) short short8;
typedef __attribute__((ext_vector_type(16))) float f32x16;

#define DEVI __device__ __forceinline__

namespace {

constexpr int DM = 2048;   // d_model
constexpr int SQ = 2048;
constexpr int SK = 2048;
constexpr int DH = 128;
constexpr int KVB = 32;            // kv rows per tile
constexpr int NT = SK / KVB;       // 64 tiles
// (1/sqrt(128)) * log2(e)
constexpr float CEXP = 0.12752051393f;
constexpr float DEFER = 62.0f;     // raw-score defer threshold (~e^8 bound)

union US8 { unsigned short u[8]; short8 v; };
union UV2 { unsigned long long q[2]; short8 v; };
union UP4 { unsigned int u[4]; short8 v; };

DEVI unsigned short f2bf(float f) {            // fp32 -> bf16 RNE
  unsigned int u = __float_as_uint(f);
  return (unsigned short)((u + 0x7fffu + ((u >> 16) & 1u)) >> 16);
}

DEVI float dq(float x) {                       // int4 quant-dequant, matches ref
  float t = __builtin_rintf(__builtin_fmaf(x, 20.0f, 8.0f));  // round half-even
  t = __builtin_fmaxf(t, 0.0f);
  t = __builtin_fminf(t, 15.0f);
  return (t - 8.0f) * 0.05f;
}

DEVI unsigned short dqb(float x) { return f2bf(dq(x)); }

} // namespace

// ---------------------------------------------------------------------------
// Prepass: dequant K/V to bf16 in ws, one (b,h,tile-of-32-rows) per block.
// K ws layout: elem u = (n*128 + d) ^ ((n&7)<<3)            [n=0..31, d=0..127]
// V ws layout: transposed, elem u = d*32 + (k ^ (((d>>1)&3)<<3))  [k=0..31]
// Both are the exact linear LDS images the main kernel stages + reads.
// ---------------------------------------------------------------------------
__global__ __launch_bounds__(512)
void eit3_pre(const float* __restrict__ kg, const float* __restrict__ vg,
              unsigned short* __restrict__ kws, unsigned short* __restrict__ vws)
{
  const int tid = threadIdx.x;
  const int t = blockIdx.x, h = blockIdx.y, b = blockIdx.z;
  const size_t tb = (((size_t)(b * 16 + h)) * NT + t) * 4096;
  // V transpose staging: stride 132 elems; col of (r,d) = d ^ (8*((r>>3)&3))
  __shared__ __align__(16) unsigned short VL[32 * 132];

  // ---- K: dest-driven (swizzle is self-inverse on the d field) ----
  {
    const int g = tid;                      // 512 groups of 8 elems
    const int n = g >> 4;
    const int dsw = ((g & 15) * 8) ^ ((n & 7) << 3);
    const float* src = kg + ((size_t)b * SK + (size_t)t * KVB + n) * DM + h * DH + dsw;
    float4 fa = *(const float4*)src;
    float4 fb = *(const float4*)(src + 4);
    US8 o;
    o.u[0] = dqb(fa.x); o.u[1] = dqb(fa.y); o.u[2] = dqb(fa.z); o.u[3] = dqb(fa.w);
    o.u[4] = dqb(fb.x); o.u[5] = dqb(fb.y); o.u[6] = dqb(fb.z); o.u[7] = dqb(fb.w);
    *(short8*)(kws + tb + (size_t)g * 8) = o.v;
  }
  // ---- V rows -> LDS (dequant, coalesced read, swizzled column group) ----
  {
    const int r = tid >> 4, dg = tid & 15;
    const float* src = vg + ((size_t)b * SK + (size_t)t * KVB + r) * DM + h * DH + dg * 8;
    float4 fa = *(const float4*)src;
    float4 fb = *(const float4*)(src + 4);
    US8 o;
    o.u[0] = dqb(fa.x); o.u[1] = dqb(fa.y); o.u[2] = dqb(fa.z); o.u[3] = dqb(fa.w);
    o.u[4] = dqb(fb.x); o.u[5] = dqb(fb.y); o.u[6] = dqb(fb.z); o.u[7] = dqb(fb.w);
    *(short8*)(VL + r * 132 + (dg ^ ((r >> 3) & 3)) * 8) = o.v;
  }
  __syncthreads();
  // ---- Vt: dest-driven transpose out of LDS, coalesced 16B ws writes ----
  {
    const int g2 = tid;                 // dest elems [g2*8, g2*8+8)
    const int d = g2 >> 2;
    const int kg = (g2 & 3) ^ ((d >> 1) & 3);
    US8 o;
#pragma unroll
    for (int i = 0; i < 8; ++i) {
      int r = kg * 8 + i;
      o.u[i] = VL[r * 132 + (d ^ (kg * 8))];
    }
    *(short8*)(vws + tb + (size_t)g2 * 8) = o.v;
  }
}

// ---------------------------------------------------------------------------
// Main attention kernel.
// ---------------------------------------------------------------------------

DEVI void proc_sub(f32x16& st, float& M, float& L, f32x16 acc[4], short8 pa[2],
                   int hi, bool fast, const unsigned char* msk, int kv0,
                   long long qlim)
{
  if (!fast) {
#pragma unroll
    for (int r = 0; r < 16; ++r) {
      int nl = (r & 3) + 8 * (r >> 2) + 4 * hi;
      bool ok = (msk[nl] != 0) && ((long long)(kv0 + nl) <= qlim);
      if (!ok) st[r] = -3.0e38f;
    }
  }
  float t8[8];
#pragma unroll
  for (int i = 0; i < 8; ++i) t8[i] = __builtin_fmaxf(st[i], st[i + 8]);
#pragma unroll
  for (int i = 0; i < 4; ++i) t8[i] = __builtin_fmaxf(t8[i], t8[i + 4]);
  float pmax = __builtin_fmaxf(__builtin_fmaxf(t8[0], t8[1]),
                               __builtin_fmaxf(t8[2], t8[3]));
  pmax = __builtin_fmaxf(pmax, __shfl_xor(pmax, 32));
  if (!__all(pmax <= M + DEFER)) {      // defer-max (T13)
    float Mn = __builtin_fmaxf(M, pmax);
    float sc = __builtin_amdgcn_exp2f((M - Mn) * CEXP);
    L *= sc;
#pragma unroll
    for (int r = 0; r < 16; ++r) {
      float s2 = __shfl(sc, (r & 3) + 8 * (r >> 2) + 4 * hi);
      acc[0][r] *= s2; acc[1][r] *= s2; acc[2][r] *= s2; acc[3][r] *= s2;
    }
    M = Mn;
  }
#pragma unroll
  for (int r = 0; r < 16; ++r)
    st[r] = __builtin_amdgcn_exp2f((st[r] - M) * CEXP);
  if (!fast) {
#pragma unroll
    for (int r = 0; r < 16; ++r) {
      int nl = (r & 3) + 8 * (r >> 2) + 4 * hi;
      bool ok = (msk[nl] != 0) && ((long long)(kv0 + nl) <= qlim);
      if (!ok) st[r] = 0.0f;
    }
  }
  float s8[8];
#pragma unroll
  for (int i = 0; i < 8; ++i) s8[i] = st[i] + st[i + 8];
#pragma unroll
  for (int i = 0; i < 4; ++i) s8[i] = s8[i] + s8[i + 4];
  float ps = (s8[0] + s8[1]) + (s8[2] + s8[3]);
  ps += __shfl_xor(ps, 32);
  L += ps;
#pragma unroll
  for (int ks = 0; ks < 2; ++ks) {      // P -> bf16 A-frags (T12)
    const int m8 = ks * 8;
    unsigned int X0, X1, Y0, Y1;
    asm("v_cvt_pk_bf16_f32 %0, %1, %2" : "=v"(X0) : "v"(st[m8 + 0]), "v"(st[m8 + 1]));
    asm("v_cvt_pk_bf16_f32 %0, %1, %2" : "=v"(X1) : "v"(st[m8 + 2]), "v"(st[m8 + 3]));
    asm("v_cvt_pk_bf16_f32 %0, %1, %2" : "=v"(Y0) : "v"(st[m8 + 4]), "v"(st[m8 + 5]));
    asm("v_cvt_pk_bf16_f32 %0, %1, %2" : "=v"(Y1) : "v"(st[m8 + 6]), "v"(st[m8 + 7]));
    asm("v_permlane32_swap_b32 %0, %1" : "+v"(X0), "+v"(Y0));
    asm("v_permlane32_swap_b32 %0, %1" : "+v"(X1), "+v"(Y1));
    UP4 P;
    P.u[0] = X0; P.u[1] = X1; P.u[2] = Y0; P.u[3] = Y1;
    pa[ks] = P.v;
  }
}

__global__ __launch_bounds__(256, 2)
void eit3_attn(const unsigned short* __restrict__ kws,
               const unsigned short* __restrict__ vws,
               const float* __restrict__ qg,
               const unsigned char* __restrict__ maskg,
               const int* __restrict__ qsg, float* __restrict__ outg)
{
  const int tid  = threadIdx.x;
  const int lane = tid & 63;
  const int w    = tid >> 6;        // wave 0..3
  const int hi   = lane >> 5;
  const int ql   = lane & 31;
  const int hi8  = hi * 8;
  // XCD-grouped decode: each XCD owns 8 bh pairs; 8 q-blocks of a bh co-located
  const int phys = blockIdx.x;              // 0..511
  const int xcd = phys & 7, slot = phys >> 3;      // slot 0..63
  const int bh = 8 * (slot >> 3) + xcd;            // 0..63
  const int qb = slot & 7;                         // 0..7
  const int h = bh & 15, b = bh >> 4;
  const int q0 = qb * 256;
  const long long qstart = (long long)qsg[0];

  __shared__ __align__(16) unsigned short Ksh[2][4096];
  __shared__ __align__(16) unsigned short Vsh[2][4096];
  __shared__ unsigned char mskSh[2][32];

  // ---- robust all-true mask check (u8 or i32 bool layouts), 8 B/thread ----
  const unsigned char* mrow = maskg + (size_t)b * SK;
  int ok_u8, ok_i32;
  {
    const unsigned int* p = (const unsigned int*)(mrow + tid * 8);
    unsigned int w0 = p[0], w1 = p[1];
    int a0 = (w0 & 0xFFu) && (w0 & 0xFF00u) && (w0 & 0xFF0000u) && (w0 & 0xFF000000u);
    int a1 = (w1 & 0xFFu) && (w1 & 0xFF00u) && (w1 & 0xFF0000u) && (w1 & 0xFF000000u);
    ok_u8  = a0 && a1;
    ok_i32 = (w0 == 1u) && (w1 == 1u);
  }
  const int a_u8  = __syncthreads_and(ok_u8);
  const int a_i32 = __syncthreads_and(ok_i32);
  const bool mask_all = (a_u8 | a_i32) != 0;

  // ---- Q fragments for 2 q-subtiles (B-operand of swapped QK^T) ----
  short8 qf0[8], qf1[8];
  {
    const float* qp0 = qg + ((size_t)b * SQ + q0 + w * 64 + ql) * DM + h * DH + hi8;
#pragma unroll
    for (int s = 0; s < 8; ++s) {
      float4 a0 = *(const float4*)(qp0 + s * 16);
      float4 c0 = *(const float4*)(qp0 + s * 16 + 4);
      float4 a1 = *(const float4*)(qp0 + 32 * DM + s * 16);
      float4 c1 = *(const float4*)(qp0 + 32 * DM + s * 16 + 4);
      US8 t0, t1;
      t0.u[0] = f2bf(a0.x); t0.u[1] = f2bf(a0.y); t0.u[2] = f2bf(a0.z); t0.u[3] = f2bf(a0.w);
      t0.u[4] = f2bf(c0.x); t0.u[5] = f2bf(c0.y); t0.u[6] = f2bf(c0.z); t0.u[7] = f2bf(c0.w);
      t1.u[0] = f2bf(a1.x); t1.u[1] = f2bf(a1.y); t1.u[2] = f2bf(a1.z); t1.u[3] = f2bf(a1.w);
      t1.u[4] = f2bf(c1.x); t1.u[5] = f2bf(c1.y); t1.u[6] = f2bf(c1.z); t1.u[7] = f2bf(c1.w);
      qf0[s] = t0.v; qf1[s] = t1.v;
    }
  }

  f32x16 zv;
#pragma unroll
  for (int r = 0; r < 16; ++r) zv[r] = 0.0f;
  f32x16 acc0[4], acc1[4];
#pragma unroll
  for (int n = 0; n < 4; ++n) { acc0[n] = zv; acc1[n] = zv; }
  float M0 = -3.0e38f, L0 = 0.0f, M1 = -3.0e38f, L1 = 0.0f;

  const size_t tbase = (size_t)bh * NT * 4096;
  const int xr = (ql & 7) << 3;        // K-row swizzle (lane-const)
  const int xv = ((ql >> 1) & 3) << 3; // Vt-row swizzle (lane-const)

  // stage tile t into buffer buf: 2 KiB per wave per tensor = 2 loads each
  auto stage = [&](int buf, int t) {
    const unsigned short* kt = kws + tbase + (size_t)t * 4096 + w * 1024 + lane * 8;
    const unsigned short* vt = vws + tbase + (size_t)t * 4096 + w * 1024 + lane * 8;
    char* kd = (char*)&Ksh[0][0] + buf * 8192 + w * 2048;
    char* vd = (char*)&Vsh[0][0] + buf * 8192 + w * 2048;
    __builtin_amdgcn_global_load_lds(
        (const __attribute__((address_space(1))) void*)kt,
        (__attribute__((address_space(3))) void*)kd, 16, 0, 0);
    __builtin_amdgcn_global_load_lds(
        (const __attribute__((address_space(1))) void*)(kt + 512),
        (__attribute__((address_space(3))) void*)(kd + 1024), 16, 0, 0);
    __builtin_amdgcn_global_load_lds(
        (const __attribute__((address_space(1))) void*)vt,
        (__attribute__((address_space(3))) void*)vd, 16, 0, 0);
    __builtin_amdgcn_global_load_lds(
        (const __attribute__((address_space(1))) void*)(vt + 512),
        (__attribute__((address_space(3))) void*)(vd + 1024), 16, 0, 0);
  };

  // prologue
  stage(0, 0);
  {
    bool f0 = mask_all && ((long long)(KVB - 1) <= qstart + (long long)q0);
    if (!f0 && w == 0 && lane < 32) mskSh[0][lane] = mrow[lane];
  }
  __syncthreads();

  int cur = 0;
  for (int ti = 0; ti < NT; ++ti) {
    const int kv0 = ti * KVB;
    const int nxt = cur ^ 1;
    if (ti + 1 < NT) {
      stage(nxt, ti + 1);
      bool fn = mask_all && ((long long)(kv0 + 2 * KVB - 1) <= qstart + (long long)q0);
      if (!fn && w == 0 && lane < 32) mskSh[nxt][lane] = mrow[kv0 + KVB + lane];
    }
    const bool fast = mask_all && ((long long)(kv0 + KVB - 1) <= qstart + (long long)q0);

    // ---- QK^T (swapped): each K-frag feeds both q-subtiles ----
    const unsigned short* Kc = &Ksh[cur][0];
    const unsigned short* Vc = &Vsh[cur][0];
    f32x16 st0 = zv, st1 = zv;
#pragma unroll
    for (int s = 0; s < 8; ++s) {
      short8 kf = *(const short8*)(Kc + ql * 128 + ((s * 16 + hi8) ^ xr));
      st0 = __builtin_amdgcn_mfma_f32_32x32x16_bf16(kf, qf0[s], st0, 0, 0, 0);
      st1 = __builtin_amdgcn_mfma_f32_32x32x16_bf16(kf, qf1[s], st1, 0, 0, 0);
    }

    // ---- online softmax per subtile ----
    short8 pa0[2], pa1[2];
    const long long qlim0 = qstart + (long long)(q0 + w * 64 + ql);
    proc_sub(st0, M0, L0, acc0, pa0, hi, fast, &mskSh[cur][0], kv0, qlim0);
    proc_sub(st1, M1, L1, acc1, pa1, hi, fast, &mskSh[cur][0], kv0, qlim0 + 32);

    // ---- PV: each Vt-frag feeds both q-subtiles ----
#pragma unroll
    for (int n = 0; n < 4; ++n) {
#pragma unroll
      for (int ks = 0; ks < 2; ++ks) {
        short8 vb = *(const short8*)(Vc + n * 1024 + ql * 32 + ((ks * 16 + hi8) ^ xv));
        acc0[n] = __builtin_amdgcn_mfma_f32_32x32x16_bf16(pa0[ks], vb, acc0[n], 0, 0, 0);
        acc1[n] = __builtin_amdgcn_mfma_f32_32x32x16_bf16(pa1[ks], vb, acc1[n], 0, 0, 0);
      }
    }

    __syncthreads();   // drains prefetch vmcnt + all reads of cur complete
    cur = nxt;
  }

  // ---- epilogue ----
  if (L0 == 0.0f) L0 = 1.0f;
  if (L1 == 0.0f) L1 = 1.0f;
  float ri0 = 1.0f / L0, ri1 = 1.0f / L1;
#pragma unroll
  for (int r = 0; r < 16; ++r) {
    int cr = (r & 3) + 8 * (r >> 2) + 4 * hi;
    float i0 = __shfl(ri0, cr), i1 = __shfl(ri1, cr);
    float* op0 = outg + ((size_t)b * SQ + q0 + w * 64 + cr) * DM + h * DH + ql;
    float* op1 = op0 + 32 * DM;
    op0[0]  = acc0[0][r] * i0;
    op0[32] = acc0[1][r] * i0;
    op0[64] = acc0[2][r] * i0;
    op0[96] = acc0[3][r] * i0;
    op1[0]  = acc1[0][r] * i1;
    op1[32] = acc1[1][r] * i1;
    op1[64] = acc1[2][r] * i1;
    op1[96] = acc1[3][r] * i1;
  }
}

// ---------------------------------------------------------------------------
// Fallback (R1 kernel, in-kernel dequant) — used only if ws is too small.
// ---------------------------------------------------------------------------
__global__ __launch_bounds__(512, 2)
void eit3_attn_fb(const float* __restrict__ qg, const float* __restrict__ kg,
                  const float* __restrict__ vg, const unsigned char* __restrict__ maskg,
                  const int* __restrict__ qsg, float* __restrict__ outg)
{
  const int tid  = threadIdx.x;
  const int lane = tid & 63;
  const int w    = tid >> 6;
  const int hi   = lane >> 5;
  const int ql   = lane & 31;
  const int qb = blockIdx.x;
  const int h  = blockIdx.y;
  const int b  = blockIdx.z;
  const int q0 = qb * 256;
  const long long qstart = (long long)qsg[0];

  __shared__ __align__(16) unsigned short Ksh[64 * 128];
  __shared__ __align__(16) unsigned short Vsh[64 * 128];
  __shared__ unsigned char mskSh[64];

  const unsigned int vbase = (unsigned int)(size_t)(void*)Vsh;

  const unsigned char* mrow = maskg + (size_t)b * SK;
  int ok_u8, ok_i32;
  {
    const unsigned char* p4 = mrow + tid * 4;
    unsigned char b0 = p4[0], b1 = p4[1], b2 = p4[2], b3 = p4[3];
    ok_u8  = (b0 && b1 && b2 && b3);
    ok_i32 = (b0 && !b1 && !b2 && !b3);
  }
  const int a_u8  = __syncthreads_and(ok_u8);
  const int a_i32 = __syncthreads_and(ok_i32);
  const bool mask_all = (a_u8 | a_i32) != 0;

  short8 qf[8];
  {
    const int qrow = q0 + w * 32 + ql;
    const float* qp = qg + ((size_t)b * SQ + qrow) * DM + h * DH + hi * 8;
#pragma unroll
    for (int s = 0; s < 8; ++s) {
      float4 fa = *(const float4*)(qp + s * 16);
      float4 fb = *(const float4*)(qp + s * 16 + 4);
      US8 t;
      t.u[0] = f2bf(fa.x); t.u[1] = f2bf(fa.y); t.u[2] = f2bf(fa.z); t.u[3] = f2bf(fa.w);
      t.u[4] = f2bf(fb.x); t.u[5] = f2bf(fb.y); t.u[6] = f2bf(fb.z); t.u[7] = f2bf(fb.w);
      qf[s] = t.v;
    }
  }

  f32x16 zv;
#pragma unroll
  for (int r = 0; r < 16; ++r) zv[r] = 0.0f;
  f32x16 acc[4];
  acc[0] = zv; acc[1] = zv; acc[2] = zv; acc[3] = zv;
  float M = -3.0e38f, L = 0.0f;

  const float* kptr = kg + ((size_t)b * SK) * DM + h * DH;
  const float* vptr = vg + ((size_t)b * SK) * DM + h * DH;

  for (int kv0 = 0; kv0 < SK; kv0 += 64) {
    __syncthreads();
#pragma unroll
    for (int j = 0; j < 2; ++j) {
      int idx = tid + 512 * j;
      int n = idx >> 4, d8 = idx & 15;
      const float* gp = kptr + (size_t)(kv0 + n) * DM + d8 * 8;
      float4 fa = *(const float4*)gp;
      float4 fb = *(const float4*)(gp + 4);
      US8 t;
      t.u[0] = dqb(fa.x); t.u[1] = dqb(fa.y); t.u[2] = dqb(fa.z); t.u[3] = dqb(fa.w);
      t.u[4] = dqb(fb.x); t.u[5] = dqb(fb.y); t.u[6] = dqb(fb.z); t.u[7] = dqb(fb.w);
      int ui = (n * 128 + d8 * 8) ^ ((n & 7) << 3);
      *(short8*)(Ksh + ui) = t.v;
    }
    {
      int kr = w * 8 + (lane & 7);
      int c3 = lane >> 3;
#pragma unroll
      for (int j = 0; j < 4; ++j) {
        int d4 = c3 + 8 * j;
        const float* gp = vptr + (size_t)(kv0 + kr) * DM + d4 * 4;
        float4 fa = *(const float4*)gp;
        ushort4 tv;
        tv.x = dqb(fa.x); tv.y = dqb(fa.y); tv.z = dqb(fa.z); tv.w = dqb(fa.w);
        int d = d4 * 4;
        int ui = ((kr >> 2) * 8 + (d >> 4)) * 64 + (kr & 3) * 16 + (d & 15);
        *(ushort4*)(Vsh + ui) = tv;
      }
    }
    const bool causal_ok = ((long long)kv0 + 63) <= (qstart + (long long)q0);
    const bool fast = mask_all && causal_ok;
    if (!fast && w == 0) mskSh[lane] = mrow[kv0 + lane];
    __syncthreads();

    f32x16 st[2];
#pragma unroll
    for (int t = 0; t < 2; ++t) {
      f32x16 sa = zv;
#pragma unroll
      for (int s = 0; s < 8; ++s) {
        int kr = t * 32 + ql;
        int ui = (kr * 128 + s * 16 + hi * 8) ^ ((kr & 7) << 3);
        short8 af = *(const short8*)(Ksh + ui);
        sa = __builtin_amdgcn_mfma_f32_32x32x16_bf16(af, qf[s], sa, 0, 0, 0);
      }
      st[t] = sa;
    }
    if (!fast) {
      const long long qlim = qstart + (long long)(q0 + w * 32 + ql);
#pragma unroll
      for (int t = 0; t < 2; ++t) {
#pragma unroll
        for (int r = 0; r < 16; ++r) {
          int nl = t * 32 + (r & 3) + 8 * (r >> 2) + 4 * hi;
          bool ok = (mskSh[nl] != 0) && ((long long)(kv0 + nl) <= qlim);
          if (!ok) st[t][r] = -3.0e38f;
        }
      }
    }
    f32x16 red;
#pragma unroll
    for (int r = 0; r < 16; ++r) red[r] = __builtin_fmaxf(st[0][r], st[1][r]);
#pragma unroll
    for (int r = 0; r < 8; ++r) red[r] = __builtin_fmaxf(red[r], red[r + 8]);
#pragma unroll
    for (int r = 0; r < 4; ++r) red[r] = __builtin_fmaxf(red[r], red[r + 4]);
    float pmax = __builtin_fmaxf(__builtin_fmaxf(red[0], red[1]),
                                 __builtin_fmaxf(red[2], red[3]));
    pmax = __builtin_fmaxf(pmax, __shfl_xor(pmax, 32));
    const float Mnew = __builtin_fmaxf(M, pmax);
    const float scale = __builtin_amdgcn_exp2f((M - Mnew) * CEXP);
#pragma unroll
    for (int t = 0; t < 2; ++t) {
#pragma unroll
      for (int r = 0; r < 16; ++r)
        st[t][r] = __builtin_amdgcn_exp2f((st[t][r] - Mnew) * CEXP);
    }
    if (!fast) {
      const long long qlim = qstart + (long long)(q0 + w * 32 + ql);
#pragma unroll
      for (int t = 0; t < 2; ++t) {
#pragma unroll
        for (int r = 0; r < 16; ++r) {
          int nl = t * 32 + (r & 3) + 8 * (r >> 2) + 4 * hi;
          bool ok = (mskSh[nl] != 0) && ((long long)(kv0 + nl) <= qlim);
          if (!ok) st[t][r] = 0.0f;
        }
      }
    }
    f32x16 sx;
#pragma unroll
    for (int r = 0; r < 16; ++r) sx[r] = st[0][r] + st[1][r];
#pragma unroll
    for (int r = 0; r < 8; ++r) sx[r] = sx[r] + sx[r + 8];
#pragma unroll
    for (int r = 0; r < 4; ++r) sx[r] = sx[r] + sx[r + 4];
    float ps = (sx[0] + sx[1]) + (sx[2] + sx[3]);
    ps += __shfl_xor(ps, 32);
    L = L * scale + ps;
    if (!__all(Mnew == M)) {
#pragma unroll
      for (int r = 0; r < 16; ++r) {
        float sc = __shfl(scale, (r & 3) + 8 * (r >> 2) + 4 * hi);
        acc[0][r] *= sc; acc[1][r] *= sc; acc[2][r] *= sc; acc[3][r] *= sc;
      }
    }
    M = Mnew;

    short8 pa[4];
#pragma unroll
    for (int ks = 0; ks < 4; ++ks) {
      const int t = ks >> 1;
      const int m8 = (ks & 1) * 8;
      unsigned int X0, X1, Y0, Y1;
      asm("v_cvt_pk_bf16_f32 %0, %1, %2" : "=v"(X0) : "v"(st[t][m8 + 0]), "v"(st[t][m8 + 1]));
      asm("v_cvt_pk_bf16_f32 %0, %1, %2" : "=v"(X1) : "v"(st[t][m8 + 2]), "v"(st[t][m8 + 3]));
      asm("v_cvt_pk_bf16_f32 %0, %1, %2" : "=v"(Y0) : "v"(st[t][m8 + 4]), "v"(st[t][m8 + 5]));
      asm("v_cvt_pk_bf16_f32 %0, %1, %2" : "=v"(Y1) : "v"(st[t][m8 + 6]), "v"(st[t][m8 + 7]));
      asm("v_permlane32_swap_b32 %0, %1" : "+v"(X0), "+v"(Y0));
      asm("v_permlane32_swap_b32 %0, %1" : "+v"(X1), "+v"(Y1));
      UP4 P;
      P.u[0] = X0; P.u[1] = X1; P.u[2] = Y0; P.u[3] = Y1;
      pa[ks] = P.v;
    }
#pragma unroll
    for (int n = 0; n < 4; ++n) {
      unsigned long long t0[4], t1[4];
#pragma unroll
      for (int ks = 0; ks < 4; ++ks) {
        unsigned int addr = vbase
          + (unsigned int)(((4 * ks + 2 * hi) * 8 + 2 * n + ((lane >> 4) & 1)) * 128)
          + (unsigned int)((lane & 15) * 8);
        asm volatile("ds_read_b64_tr_b16 %0, %1" : "=v"(t0[ks]) : "v"(addr));
        asm volatile("ds_read_b64_tr_b16 %0, %1 offset:1024" : "=v"(t1[ks]) : "v"(addr));
      }
      asm volatile("s_waitcnt lgkmcnt(0)" ::: "memory");
      __builtin_amdgcn_sched_barrier(0);
#pragma unroll
      for (int ks = 0; ks < 4; ++ks) {
        UV2 vb;
        vb.q[0] = t0[ks]; vb.q[1] = t1[ks];
        acc[n] = __builtin_amdgcn_mfma_f32_32x32x16_bf16(pa[ks], vb.v, acc[n], 0, 0, 0);
      }
    }
  }

  if (L == 0.0f) L = 1.0f;
  float rinv = 1.0f / L;
#pragma unroll
  for (int r = 0; r < 16; ++r) {
    int cr = (r & 3) + 8 * (r >> 2) + 4 * hi;
    float inv = __shfl(rinv, cr);
    float* op = outg + ((size_t)b * SQ + (q0 + w * 32 + cr)) * DM + h * DH + ql;
    op[0]  = acc[0][r] * inv;
    op[32] = acc[1][r] * inv;
    op[64] = acc[2][r] * inv;
    op[96] = acc[3][r] * inv;
  }
}

extern "C" void kernel_launch(void* const* d_in, const int* in_sizes, int n_in,
                              void* d_out, int out_size, void* d_ws, size_t ws_size,
                              hipStream_t stream) {
  (void)in_sizes; (void)n_in; (void)out_size;
  const float* q = (const float*)d_in[0];
  const float* k = (const float*)d_in[1];
  const float* v = (const float*)d_in[2];
  const unsigned char* mask = (const unsigned char*)d_in[3];
  const int* qs = (const int*)d_in[4];

  const size_t need = (size_t)2 * 16777216 * 2;   // K + V bf16 = 64 MiB
  if (ws_size >= need) {
    unsigned short* kws = (unsigned short*)d_ws;
    unsigned short* vws = kws + 16777216;
    dim3 pgrid(NT, 16, 4);
    eit3_pre<<<pgrid, dim3(512), 0, stream>>>(k, v, kws, vws);
    eit3_attn<<<dim3(512), dim3(256), 0, stream>>>(kws, vws, q, mask, qs, (float*)d_out);
  } else {
    dim3 grid(SQ / 256, 16, 4);
    eit3_attn_fb<<<grid, dim3(512), 0, stream>>>(q, k, v, mask, qs, (float*)d_out);
  }
}

// Round 4
// 219.792 us; speedup vs baseline: 1.3522x; 1.3471x over previous
//
#include <hip/hip_runtime.h>

// EIT3Attention: B=4, Sq=Sk=2048, d_model=2048, H=16, Dh=128, fp32 I/O.
// R4: prepass dequants K/V -> bf16 ws (K row-major XOR-swizzled 64-row tiles,
// V^T d-major XOR-swizzled). Main: 8-wave/512-thr, 32 q-rows/wave (R1's
// verified shapes), KVB=64, global_load_lds staging (4 instr/wave/iter),
// double buffer, defer-max, setprio. R2/R3 lesson: 64q needs >256 regs ->
// spills; 32q fits (acc 64 AGPR + ~120 arch VGPR).

typedef __attribute__((ext_vector_type(8))) short short8;
typedef __attribute__((ext_vector_type(16))) float f32x16;

#define DEVI __device__ __forceinline__

namespace {

constexpr int DM = 2048;   // d_model
constexpr int SQ = 2048;
constexpr int SK = 2048;
constexpr int DH = 128;
constexpr int KVB = 64;            // kv rows per tile
constexpr int NT = SK / KVB;       // 32 tiles
constexpr int TILE_E = KVB * DH;   // 8192 elems per tensor-tile
// (1/sqrt(128)) * log2(e)
constexpr float CEXP = 0.12752051393f;
constexpr float DEFER = 62.0f;     // raw-score defer threshold (~e^7.9 bound)

union US8 { unsigned short u[8]; short8 v; };
union UP4 { unsigned int u[4]; short8 v; };

DEVI unsigned short f2bf(float f) {            // fp32 -> bf16 RNE
  unsigned int u = __float_as_uint(f);
  return (unsigned short)((u + 0x7fffu + ((u >> 16) & 1u)) >> 16);
}

DEVI float dq(float x) {                       // int4 quant-dequant, matches ref
  float t = __builtin_rintf(__builtin_fmaf(x, 20.0f, 8.0f));  // round half-even
  t = __builtin_fmaxf(t, 0.0f);
  t = __builtin_fminf(t, 15.0f);
  return (t - 8.0f) * 0.05f;
}

DEVI unsigned short dqb(float x) { return f2bf(dq(x)); }

} // namespace

// ---------------------------------------------------------------------------
// Prepass: dequant K/V -> bf16 ws, one (b,h,tile-of-64-rows) per block.
// K ws tile layout: elem u = (n*128 + d) ^ ((n&7)<<3)      [n=0..63, d=0..127]
// V ws tile layout: transposed, elem u = d*64 + (k ^ ((d&7)<<3))   [k=0..63]
// Both are the exact linear LDS images the main kernel stages + reads.
// ---------------------------------------------------------------------------
__global__ __launch_bounds__(512)
void eit3_pre(const float* __restrict__ kg, const float* __restrict__ vg,
              unsigned short* __restrict__ kws, unsigned short* __restrict__ vws)
{
  const int tid = threadIdx.x;
  const int t = blockIdx.x, h = blockIdx.y, b = blockIdx.z;
  const size_t tb = (((size_t)(b * 16 + h)) * NT + t) * TILE_E;
  // V transpose staging: [64][136]; V[r][d] at col ((d>>3 ^ (r&7))*8 + (d&7))
  __shared__ __align__(16) unsigned short VL[64 * 136];

  // ---- K: dest-driven (row swizzle is self-inverse on the d field) ----
#pragma unroll
  for (int j = 0; j < 2; ++j) {
    const int G = tid + j * 512;            // 1024 granules of 8 elems
    const int n = G >> 4;
    const int dsw = ((G & 15) * 8) ^ ((n & 7) << 3);
    const float* src = kg + ((size_t)b * SK + (size_t)t * KVB + n) * DM + h * DH + dsw;
    float4 fa = *(const float4*)src;
    float4 fb = *(const float4*)(src + 4);
    US8 o;
    o.u[0] = dqb(fa.x); o.u[1] = dqb(fa.y); o.u[2] = dqb(fa.z); o.u[3] = dqb(fa.w);
    o.u[4] = dqb(fb.x); o.u[5] = dqb(fb.y); o.u[6] = dqb(fb.z); o.u[7] = dqb(fb.w);
    *(short8*)(kws + tb + (size_t)G * 8) = o.v;
  }
  // ---- V rows -> LDS (dequant, coalesced read, granule-swizzled cols) ----
  {
    const int r = tid >> 3;                 // 0..63
    const int d0 = (tid & 7) * 16;          // 16 elems per thread
    const int c8 = d0 >> 3;                 // 2 granules
    const float* src = vg + ((size_t)b * SK + (size_t)t * KVB + r) * DM + h * DH + d0;
    US8 o0, o1;
#pragma unroll
    for (int j = 0; j < 4; ++j) {
      float4 f = *(const float4*)(src + j * 4);
      unsigned short* o = (j < 2) ? o0.u + j * 4 : o1.u + (j - 2) * 4;
      o[0] = dqb(f.x); o[1] = dqb(f.y); o[2] = dqb(f.z); o[3] = dqb(f.w);
    }
    *(short8*)(VL + r * 136 + ((c8 ^ (r & 7)) * 8)) = o0.v;
    *(short8*)(VL + r * 136 + (((c8 + 1) ^ (r & 7)) * 8)) = o1.v;
  }
  __syncthreads();
  // ---- V^T: dest-driven transpose out of LDS, coalesced 16B ws writes ----
#pragma unroll
  for (int j = 0; j < 2; ++j) {
    const int G = tid + j * 512;            // 1024 dest granules
    const int d = G >> 3;
    const int k0 = ((G & 7) ^ (d & 7)) * 8;
    US8 o;
#pragma unroll
    for (int i = 0; i < 8; ++i)
      o.u[i] = VL[(k0 + i) * 136 + (((d >> 3) ^ i) * 8) + (d & 7)];
    *(short8*)(vws + tb + (size_t)G * 8) = o.v;
  }
}

// ---------------------------------------------------------------------------
// Main attention kernel: 8 waves, 32 q-rows/wave, KVB=64, double-buffered.
// ---------------------------------------------------------------------------
__global__ __launch_bounds__(512, 2)
void eit3_attn(const unsigned short* __restrict__ kws,
               const unsigned short* __restrict__ vws,
               const float* __restrict__ qg,
               const unsigned char* __restrict__ maskg,
               const int* __restrict__ qsg, float* __restrict__ outg)
{
  const int tid  = threadIdx.x;
  const int lane = tid & 63;
  const int w    = tid >> 6;        // wave 0..7
  const int hi   = lane >> 5;
  const int ql   = lane & 31;
  const int hi8  = hi * 8;
  // XCD-grouped decode: XCD x owns bh in {8g+x}; all 8 q-blocks of a bh
  // plus 8 bh co-resident per XCD -> ws streams are L2 hits after 1st touch.
  const int phys = blockIdx.x;                     // 0..511
  const int xcd = phys & 7, slot = phys >> 3;      // slot 0..63
  const int bh = 8 * (slot >> 3) + xcd;            // 0..63
  const int qb = slot & 7;                         // 0..7
  const int h = bh & 15, b = bh >> 4;
  const int q0 = qb * 256;
  const long long qstart = (long long)qsg[0];

  __shared__ __align__(16) unsigned short Ksh[2][TILE_E];
  __shared__ __align__(16) unsigned short Vsh[2][TILE_E];
  __shared__ unsigned char mskSh[2][64];

  // ---- robust all-true mask check (u8 or i32 bool layouts) ----
  const unsigned char* mrow = maskg + (size_t)b * SK;
  int ok_u8, ok_i32;
  {
    const unsigned char* p4 = mrow + tid * 4;
    unsigned char b0 = p4[0], b1 = p4[1], b2 = p4[2], b3 = p4[3];
    ok_u8  = (b0 && b1 && b2 && b3);
    ok_i32 = (b0 && !b1 && !b2 && !b3);
  }
  const int a_u8  = __syncthreads_and(ok_u8);
  const int a_i32 = __syncthreads_and(ok_i32);
  const bool mask_all = (a_u8 | a_i32) != 0;

  const size_t tbase = (size_t)bh * NT * TILE_E;

  // stage tile t into buffer buf: 2 KiB per wave per tensor = 4 gll instrs
  auto stage = [&](int buf, int t) {
    const unsigned short* kt = kws + tbase + (size_t)t * TILE_E + w * 1024 + lane * 8;
    const unsigned short* vt = vws + tbase + (size_t)t * TILE_E + w * 1024 + lane * 8;
    char* kd = (char*)&Ksh[0][0] + buf * (TILE_E * 2) + w * 2048;
    char* vd = (char*)&Vsh[0][0] + buf * (TILE_E * 2) + w * 2048;
    __builtin_amdgcn_global_load_lds(
        (const __attribute__((address_space(1))) void*)kt,
        (__attribute__((address_space(3))) void*)kd, 16, 0, 0);
    __builtin_amdgcn_global_load_lds(
        (const __attribute__((address_space(1))) void*)(kt + 512),
        (__attribute__((address_space(3))) void*)(kd + 1024), 16, 0, 0);
    __builtin_amdgcn_global_load_lds(
        (const __attribute__((address_space(1))) void*)vt,
        (__attribute__((address_space(3))) void*)vd, 16, 0, 0);
    __builtin_amdgcn_global_load_lds(
        (const __attribute__((address_space(1))) void*)(vt + 512),
        (__attribute__((address_space(3))) void*)(vd + 1024), 16, 0, 0);
  };

  stage(0, 0);   // issue first-tile staging before Q loads

  // ---- Q fragments (B-operand of swapped QK^T): lane holds Q[q][16s+8hi+i] ----
  short8 qf[8];
  {
    const float* qp = qg + ((size_t)b * SQ + q0 + w * 32 + ql) * DM + h * DH + hi8;
#pragma unroll
    for (int s = 0; s < 8; ++s) {
      float4 fa = *(const float4*)(qp + s * 16);
      float4 fb = *(const float4*)(qp + s * 16 + 4);
      US8 t;
      t.u[0] = f2bf(fa.x); t.u[1] = f2bf(fa.y); t.u[2] = f2bf(fa.z); t.u[3] = f2bf(fa.w);
      t.u[4] = f2bf(fb.x); t.u[5] = f2bf(fb.y); t.u[6] = f2bf(fb.z); t.u[7] = f2bf(fb.w);
      qf[s] = t.v;
    }
  }

  f32x16 zv;
#pragma unroll
  for (int r = 0; r < 16; ++r) zv[r] = 0.0f;
  f32x16 acc[4];
  acc[0] = zv; acc[1] = zv; acc[2] = zv; acc[3] = zv;
  float M = -3.0e38f, L = 0.0f;
  const long long qlim = qstart + (long long)(q0 + w * 32 + ql);

  {
    bool f0 = mask_all && ((long long)(KVB - 1) <= qstart + (long long)q0);
    if (!f0 && w == 0) mskSh[0][lane] = mrow[lane];
  }
  __syncthreads();   // drains stage(0) vmcnt

  int cur = 0;
  for (int ti = 0; ti < NT; ++ti) {
    const int kv0 = ti * KVB;
    const int nxt = cur ^ 1;
    if (ti + 1 < NT) {
      stage(nxt, ti + 1);
      bool fn = mask_all && ((long long)(kv0 + 2 * KVB - 1) <= qstart + (long long)q0);
      if (!fn && w == 0) mskSh[nxt][lane] = mrow[kv0 + KVB + lane];
    }
    const bool fast = mask_all && ((long long)(kv0 + KVB - 1) <= qstart + (long long)q0);

    const unsigned short* Kc = &Ksh[cur][0];
    const unsigned short* Vc = &Vsh[cur][0];

    // ---- QK^T (swapped): S^T[k][q] = Kd[k][:]·Q[q][:] ----
    f32x16 st[2];
    __builtin_amdgcn_s_setprio(1);
#pragma unroll
    for (int t = 0; t < 2; ++t) {
      f32x16 sa = zv;
#pragma unroll
      for (int s = 0; s < 8; ++s) {
        int kr = t * 32 + ql;
        short8 af = *(const short8*)(Kc + kr * 128 + ((s * 16 + hi8) ^ ((kr & 7) << 3)));
        sa = __builtin_amdgcn_mfma_f32_32x32x16_bf16(af, qf[s], sa, 0, 0, 0);
      }
      st[t] = sa;
    }
    __builtin_amdgcn_s_setprio(0);

    // ---- masking (slow path only) ----
    if (!fast) {
#pragma unroll
      for (int t = 0; t < 2; ++t) {
#pragma unroll
        for (int r = 0; r < 16; ++r) {
          int nl = t * 32 + (r & 3) + 8 * (r >> 2) + 4 * hi;
          bool ok = (mskSh[cur][nl] != 0) && ((long long)(kv0 + nl) <= qlim);
          if (!ok) st[t][r] = -3.0e38f;
        }
      }
    }

    // ---- online softmax (defer-max): lane owns q-col; pair lane^32 -> 64 k ----
    f32x16 red;
#pragma unroll
    for (int r = 0; r < 16; ++r) red[r] = __builtin_fmaxf(st[0][r], st[1][r]);
#pragma unroll
    for (int r = 0; r < 8; ++r) red[r] = __builtin_fmaxf(red[r], red[r + 8]);
#pragma unroll
    for (int r = 0; r < 4; ++r) red[r] = __builtin_fmaxf(red[r], red[r + 4]);
    float pmax = __builtin_fmaxf(__builtin_fmaxf(red[0], red[1]),
                                 __builtin_fmaxf(red[2], red[3]));
    pmax = __builtin_fmaxf(pmax, __shfl_xor(pmax, 32));
    if (!__all(pmax <= M + DEFER)) {        // T13: rescale only on real growth
      float Mn = __builtin_fmaxf(M, pmax);
      float sc = __builtin_amdgcn_exp2f((M - Mn) * CEXP);
      L *= sc;
#pragma unroll
      for (int r = 0; r < 16; ++r) {
        float s2 = __shfl(sc, (r & 3) + 8 * (r >> 2) + 4 * hi);
        acc[0][r] *= s2; acc[1][r] *= s2; acc[2][r] *= s2; acc[3][r] *= s2;
      }
      M = Mn;
    }
#pragma unroll
    for (int t = 0; t < 2; ++t) {
#pragma unroll
      for (int r = 0; r < 16; ++r)
        st[t][r] = __builtin_amdgcn_exp2f((st[t][r] - M) * CEXP);
    }
    if (!fast) {   // force masked p to exactly 0 (handles all-masked tiles)
#pragma unroll
      for (int t = 0; t < 2; ++t) {
#pragma unroll
        for (int r = 0; r < 16; ++r) {
          int nl = t * 32 + (r & 3) + 8 * (r >> 2) + 4 * hi;
          bool ok = (mskSh[cur][nl] != 0) && ((long long)(kv0 + nl) <= qlim);
          if (!ok) st[t][r] = 0.0f;
        }
      }
    }
    f32x16 sx;
#pragma unroll
    for (int r = 0; r < 16; ++r) sx[r] = st[0][r] + st[1][r];
#pragma unroll
    for (int r = 0; r < 8; ++r) sx[r] = sx[r] + sx[r + 8];
#pragma unroll
    for (int r = 0; r < 4; ++r) sx[r] = sx[r] + sx[r + 4];
    float ps = (sx[0] + sx[1]) + (sx[2] + sx[3]);
    ps += __shfl_xor(ps, 32);
    L += ps;

    // ---- P -> bf16 A-frags: cvt_pk pairs + permlane32_swap (T12) ----
    short8 pa[4];
#pragma unroll
    for (int ks = 0; ks < 4; ++ks) {
      const int t = ks >> 1;
      const int m8 = (ks & 1) * 8;
      unsigned int X0, X1, Y0, Y1;
      asm("v_cvt_pk_bf16_f32 %0, %1, %2" : "=v"(X0) : "v"(st[t][m8 + 0]), "v"(st[t][m8 + 1]));
      asm("v_cvt_pk_bf16_f32 %0, %1, %2" : "=v"(X1) : "v"(st[t][m8 + 2]), "v"(st[t][m8 + 3]));
      asm("v_cvt_pk_bf16_f32 %0, %1, %2" : "=v"(Y0) : "v"(st[t][m8 + 4]), "v"(st[t][m8 + 5]));
      asm("v_cvt_pk_bf16_f32 %0, %1, %2" : "=v"(Y1) : "v"(st[t][m8 + 6]), "v"(st[t][m8 + 7]));
      asm("v_permlane32_swap_b32 %0, %1" : "+v"(X0), "+v"(Y0));
      asm("v_permlane32_swap_b32 %0, %1" : "+v"(X1), "+v"(Y1));
      UP4 P;
      P.u[0] = X0; P.u[1] = X1; P.u[2] = Y0; P.u[3] = Y1;
      pa[ks] = P.v;
    }

    // ---- PV: out[q][d] += P[q][k]·Vd[k][d]; B-frag from V^T LDS ----
    __builtin_amdgcn_s_setprio(1);
#pragma unroll
    for (int n = 0; n < 4; ++n) {
      const unsigned short* vrow = Vc + n * 2048 + ql * 64;
#pragma unroll
      for (int ks = 0; ks < 4; ++ks) {
        short8 vb = *(const short8*)(vrow + ((ks * 16 + hi8) ^ ((ql & 7) << 3)));
        acc[n] = __builtin_amdgcn_mfma_f32_32x32x16_bf16(pa[ks], vb, acc[n], 0, 0, 0);
      }
    }
    __builtin_amdgcn_s_setprio(0);

    __syncthreads();   // all reads of cur done + prefetch vmcnt drained
    cur = nxt;
  }

  // ---- epilogue: out = acc / L ----
  if (L == 0.0f) L = 1.0f;
  float rinv = 1.0f / L;
#pragma unroll
  for (int r = 0; r < 16; ++r) {
    int cr = (r & 3) + 8 * (r >> 2) + 4 * hi;
    float inv = __shfl(rinv, cr);
    float* op = outg + ((size_t)b * SQ + q0 + w * 32 + cr) * DM + h * DH + ql;
    op[0]  = acc[0][r] * inv;
    op[32] = acc[1][r] * inv;
    op[64] = acc[2][r] * inv;
    op[96] = acc[3][r] * inv;
  }
}

// ---------------------------------------------------------------------------
// Fallback (R1 kernel, in-kernel dequant) — used only if ws is too small.
// ---------------------------------------------------------------------------
__global__ __launch_bounds__(512, 2)
void eit3_attn_fb(const float* __restrict__ qg, const float* __restrict__ kg,
                  const float* __restrict__ vg, const unsigned char* __restrict__ maskg,
                  const int* __restrict__ qsg, float* __restrict__ outg)
{
  const int tid  = threadIdx.x;
  const int lane = tid & 63;
  const int w    = tid >> 6;
  const int hi   = lane >> 5;
  const int ql   = lane & 31;
  const int qb = blockIdx.x;
  const int h  = blockIdx.y;
  const int b  = blockIdx.z;
  const int q0 = qb * 256;
  const long long qstart = (long long)qsg[0];

  __shared__ __align__(16) unsigned short Ksh[64 * 128];
  __shared__ __align__(16) unsigned short Vsh[64 * 128];
  __shared__ unsigned char mskSh[64];

  const unsigned int vbase = (unsigned int)(size_t)(void*)Vsh;

  const unsigned char* mrow = maskg + (size_t)b * SK;
  int ok_u8, ok_i32;
  {
    const unsigned char* p4 = mrow + tid * 4;
    unsigned char b0 = p4[0], b1 = p4[1], b2 = p4[2], b3 = p4[3];
    ok_u8  = (b0 && b1 && b2 && b3);
    ok_i32 = (b0 && !b1 && !b2 && !b3);
  }
  const int a_u8  = __syncthreads_and(ok_u8);
  const int a_i32 = __syncthreads_and(ok_i32);
  const bool mask_all = (a_u8 | a_i32) != 0;

  short8 qf[8];
  {
    const int qrow = q0 + w * 32 + ql;
    const float* qp = qg + ((size_t)b * SQ + qrow) * DM + h * DH + hi * 8;
#pragma unroll
    for (int s = 0; s < 8; ++s) {
      float4 fa = *(const float4*)(qp + s * 16);
      float4 fb = *(const float4*)(qp + s * 16 + 4);
      US8 t;
      t.u[0] = f2bf(fa.x); t.u[1] = f2bf(fa.y); t.u[2] = f2bf(fa.z); t.u[3] = f2bf(fa.w);
      t.u[4] = f2bf(fb.x); t.u[5] = f2bf(fb.y); t.u[6] = f2bf(fb.z); t.u[7] = f2bf(fb.w);
      qf[s] = t.v;
    }
  }

  f32x16 zv;
#pragma unroll
  for (int r = 0; r < 16; ++r) zv[r] = 0.0f;
  f32x16 acc[4];
  acc[0] = zv; acc[1] = zv; acc[2] = zv; acc[3] = zv;
  float M = -3.0e38f, L = 0.0f;

  const float* kptr = kg + ((size_t)b * SK) * DM + h * DH;
  const float* vptr = vg + ((size_t)b * SK) * DM + h * DH;

  for (int kv0 = 0; kv0 < SK; kv0 += 64) {
    __syncthreads();
#pragma unroll
    for (int j = 0; j < 2; ++j) {
      int idx = tid + 512 * j;
      int n = idx >> 4, d8 = idx & 15;
      const float* gp = kptr + (size_t)(kv0 + n) * DM + d8 * 8;
      float4 fa = *(const float4*)gp;
      float4 fb = *(const float4*)(gp + 4);
      US8 t;
      t.u[0] = dqb(fa.x); t.u[1] = dqb(fa.y); t.u[2] = dqb(fa.z); t.u[3] = dqb(fa.w);
      t.u[4] = dqb(fb.x); t.u[5] = dqb(fb.y); t.u[6] = dqb(fb.z); t.u[7] = dqb(fb.w);
      int ui = (n * 128 + d8 * 8) ^ ((n & 7) << 3);
      *(short8*)(Ksh + ui) = t.v;
    }
    {
      int kr = w * 8 + (lane & 7);
      int c3 = lane >> 3;
#pragma unroll
      for (int j = 0; j < 4; ++j) {
        int d4 = c3 + 8 * j;
        const float* gp = vptr + (size_t)(kv0 + kr) * DM + d4 * 4;
        float4 fa = *(const float4*)gp;
        ushort4 tv;
        tv.x = dqb(fa.x); tv.y = dqb(fa.y); tv.z = dqb(fa.z); tv.w = dqb(fa.w);
        int d = d4 * 4;
        int ui = ((kr >> 2) * 8 + (d >> 4)) * 64 + (kr & 3) * 16 + (d & 15);
        *(ushort4*)(Vsh + ui) = tv;
      }
    }
    const bool causal_ok = ((long long)kv0 + 63) <= (qstart + (long long)q0);
    const bool fast = mask_all && causal_ok;
    if (!fast && w == 0) mskSh[lane] = mrow[kv0 + lane];
    __syncthreads();

    f32x16 st[2];
#pragma unroll
    for (int t = 0; t < 2; ++t) {
      f32x16 sa = zv;
#pragma unroll
      for (int s = 0; s < 8; ++s) {
        int kr = t * 32 + ql;
        int ui = (kr * 128 + s * 16 + hi * 8) ^ ((kr & 7) << 3);
        short8 af = *(const short8*)(Ksh + ui);
        sa = __builtin_amdgcn_mfma_f32_32x32x16_bf16(af, qf[s], sa, 0, 0, 0);
      }
      st[t] = sa;
    }
    if (!fast) {
      const long long qlim = qstart + (long long)(q0 + w * 32 + ql);
#pragma unroll
      for (int t = 0; t < 2; ++t) {
#pragma unroll
        for (int r = 0; r < 16; ++r) {
          int nl = t * 32 + (r & 3) + 8 * (r >> 2) + 4 * hi;
          bool ok = (mskSh[nl] != 0) && ((long long)(kv0 + nl) <= qlim);
          if (!ok) st[t][r] = -3.0e38f;
        }
      }
    }
    f32x16 red;
#pragma unroll
    for (int r = 0; r < 16; ++r) red[r] = __builtin_fmaxf(st[0][r], st[1][r]);
#pragma unroll
    for (int r = 0; r < 8; ++r) red[r] = __builtin_fmaxf(red[r], red[r + 8]);
#pragma unroll
    for (int r = 0; r < 4; ++r) red[r] = __builtin_fmaxf(red[r], red[r + 4]);
    float pmax = __builtin_fmaxf(__builtin_fmaxf(red[0], red[1]),
                                 __builtin_fmaxf(red[2], red[3]));
    pmax = __builtin_fmaxf(pmax, __shfl_xor(pmax, 32));
    const float Mnew = __builtin_fmaxf(M, pmax);
    const float scale = __builtin_amdgcn_exp2f((M - Mnew) * CEXP);
#pragma unroll
    for (int t = 0; t < 2; ++t) {
#pragma unroll
      for (int r = 0; r < 16; ++r)
        st[t][r] = __builtin_amdgcn_exp2f((st[t][r] - Mnew) * CEXP);
    }
    if (!fast) {
      const long long qlim = qstart + (long long)(q0 + w * 32 + ql);
#pragma unroll
      for (int t = 0; t < 2; ++t) {
#pragma unroll
        for (int r = 0; r < 16; ++r) {
          int nl = t * 32 + (r & 3) + 8 * (r >> 2) + 4 * hi;
          bool ok = (mskSh[nl] != 0) && ((long long)(kv0 + nl) <= qlim);
          if (!ok) st[t][r] = 0.0f;
        }
      }
    }
    f32x16 sx;
#pragma unroll
    for (int r = 0; r < 16; ++r) sx[r] = st[0][r] + st[1][r];
#pragma unroll
    for (int r = 0; r < 8; ++r) sx[r] = sx[r] + sx[r + 8];
#pragma unroll
    for (int r = 0; r < 4; ++r) sx[r] = sx[r] + sx[r + 4];
    float ps = (sx[0] + sx[1]) + (sx[2] + sx[3]);
    ps += __shfl_xor(ps, 32);
    L = L * scale + ps;
    if (!__all(Mnew == M)) {
#pragma unroll
      for (int r = 0; r < 16; ++r) {
        float sc = __shfl(scale, (r & 3) + 8 * (r >> 2) + 4 * hi);
        acc[0][r] *= sc; acc[1][r] *= sc; acc[2][r] *= sc; acc[3][r] *= sc;
      }
    }
    M = Mnew;

    short8 pa[4];
#pragma unroll
    for (int ks = 0; ks < 4; ++ks) {
      const int t = ks >> 1;
      const int m8 = (ks & 1) * 8;
      unsigned int X0, X1, Y0, Y1;
      asm("v_cvt_pk_bf16_f32 %0, %1, %2" : "=v"(X0) : "v"(st[t][m8 + 0]), "v"(st[t][m8 + 1]));
      asm("v_cvt_pk_bf16_f32 %0, %1, %2" : "=v"(X1) : "v"(st[t][m8 + 2]), "v"(st[t][m8 + 3]));
      asm("v_cvt_pk_bf16_f32 %0, %1, %2" : "=v"(Y0) : "v"(st[t][m8 + 4]), "v"(st[t][m8 + 5]));
      asm("v_cvt_pk_bf16_f32 %0, %1, %2" : "=v"(Y1) : "v"(st[t][m8 + 6]), "v"(st[t][m8 + 7]));
      asm("v_permlane32_swap_b32 %0, %1" : "+v"(X0), "+v"(Y0));
      asm("v_permlane32_swap_b32 %0, %1" : "+v"(X1), "+v"(Y1));
      UP4 P;
      P.u[0] = X0; P.u[1] = X1; P.u[2] = Y0; P.u[3] = Y1;
      pa[ks] = P.v;
    }
#pragma unroll
    for (int n = 0; n < 4; ++n) {
      unsigned long long t0[4], t1[4];
#pragma unroll
      for (int ks = 0; ks < 4; ++ks) {
        unsigned int addr = vbase
          + (unsigned int)(((4 * ks + 2 * hi) * 8 + 2 * n + ((lane >> 4) & 1)) * 128)
          + (unsigned int)((lane & 15) * 8);
        asm volatile("ds_read_b64_tr_b16 %0, %1" : "=v"(t0[ks]) : "v"(addr));
        asm volatile("ds_read_b64_tr_b16 %0, %1 offset:1024" : "=v"(t1[ks]) : "v"(addr));
      }
      asm volatile("s_waitcnt lgkmcnt(0)" ::: "memory");
      __builtin_amdgcn_sched_barrier(0);
#pragma unroll
      for (int ks = 0; ks < 4; ++ks) {
        union { unsigned long long q[2]; short8 v; } vb;
        vb.q[0] = t0[ks]; vb.q[1] = t1[ks];
        acc[n] = __builtin_amdgcn_mfma_f32_32x32x16_bf16(pa[ks], vb.v, acc[n], 0, 0, 0);
      }
    }
  }

  if (L == 0.0f) L = 1.0f;
  float rinv = 1.0f / L;
#pragma unroll
  for (int r = 0; r < 16; ++r) {
    int cr = (r & 3) + 8 * (r >> 2) + 4 * hi;
    float inv = __shfl(rinv, cr);
    float* op = outg + ((size_t)b * SQ + (q0 + w * 32 + cr)) * DM + h * DH + ql;
    op[0]  = acc[0][r] * inv;
    op[32] = acc[1][r] * inv;
    op[64] = acc[2][r] * inv;
    op[96] = acc[3][r] * inv;
  }
}

extern "C" void kernel_launch(void* const* d_in, const int* in_sizes, int n_in,
                              void* d_out, int out_size, void* d_ws, size_t ws_size,
                              hipStream_t stream) {
  (void)in_sizes; (void)n_in; (void)out_size;
  const float* q = (const float*)d_in[0];
  const float* k = (const float*)d_in[1];
  const float* v = (const float*)d_in[2];
  const unsigned char* mask = (const unsigned char*)d_in[3];
  const int* qs = (const int*)d_in[4];

  const size_t need = (size_t)2 * 16777216 * 2;   // K + V bf16 = 64 MiB
  if (ws_size >= need) {
    unsigned short* kws = (unsigned short*)d_ws;
    unsigned short* vws = kws + 16777216;
    dim3 pgrid(NT, 16, 4);
    eit3_pre<<<pgrid, dim3(512), 0, stream>>>(k, v, kws, vws);
    eit3_attn<<<dim3(512), dim3(512), 0, stream>>>(kws, vws, q, mask, qs, (float*)d_out);
  } else {
    dim3 grid(SQ / 256, 16, 4);
    eit3_attn_fb<<<grid, dim3(512), 0, stream>>>(q, k, v, mask, qs, (float*)d_out);
  }
}